// Round 3
// baseline (1226.024 us; speedup 1.0000x reference)
//
#include <hip/hip_runtime.h>

#define BB 512
#define LL 1024
#define DD 16
#define HH 64
#define CH 32    // timesteps per chunk
#define XS 20    // sh_x row stride (uints)  - padded vs 16 to break conflicts
#define GS 196   // sh_gi row stride (floats) - padded vs 192
#define HS 68    // sh_hb row stride (uints)  - padded vs 64

typedef _Float16 half8 __attribute__((ext_vector_type(8)));
typedef float floatx4 __attribute__((ext_vector_type(4)));

struct U4 { unsigned x, y, z, w; };

__device__ __forceinline__ float sigmoidf_(float x) {
    return __builtin_amdgcn_rcpf(1.0f + __expf(-x));
}
__device__ __forceinline__ float tanhf_(float x) {
    x = fminf(fmaxf(x, -15.0f), 15.0f);
    float e = __expf(2.0f * x);
    return (e - 1.0f) * __builtin_amdgcn_rcpf(e + 1.0f);
}
// split v into f16 hi + f16 lo (v ~= hi + lo, error ~2^-22 rel)
__device__ __forceinline__ void split_(float v, unsigned& h, unsigned& l) {
    _Float16 hf = (_Float16)v;
    float rr = v - (float)hf;
    _Float16 lf = (_Float16)rr;
    h = (unsigned)__builtin_bit_cast(unsigned short, hf);
    l = (unsigned)__builtin_bit_cast(unsigned short, lf);
}
// packed = (lo16 << 16) | hi16  -> verbatim (elem2r=hi, elem2r+1=lo) K-pair
__device__ __forceinline__ unsigned pack_hl(float v) {
    unsigned h, l; split_(v, h, l);
    return h | (l << 16);
}
__device__ __forceinline__ half8 h8(U4 u) { return __builtin_bit_cast(half8, u); }

#define MFMA(a, b, c) __builtin_amdgcn_mfma_f32_16x16x32_f16((a), (b), (c), 0, 0, 0)

// One wave per (dir, batch). Weights live as f16 hi/lo MFMA A-fragments
// (AGPR-native). Recurrent matvec: B col0=h_hi, col1=h_lo via ds_bpermute.
// gi (Wih*x) and y (Wout*h) are chunk-batched MFMAs at full column use.
__global__ __launch_bounds__(64, 1) void brios_main(
    const float* __restrict__ x, const float* __restrict__ dt,
    const float* __restrict__ f_Wih, const float* __restrict__ f_Whh,
    const float* __restrict__ f_bih, const float* __restrict__ f_bhh,
    const float* __restrict__ f_gamma, const float* __restrict__ f_Wout,
    const float* __restrict__ f_bout,
    const float* __restrict__ b_Wih, const float* __restrict__ b_Whh,
    const float* __restrict__ b_bih, const float* __restrict__ b_bhh,
    const float* __restrict__ b_gamma, const float* __restrict__ b_Wout,
    const float* __restrict__ b_bout,
    float* __restrict__ out)
{
    const int lane = threadIdx.x;
    const int dir  = blockIdx.x >> 9;
    const int b    = blockIdx.x & 511;
    const int m    = lane & 15;      // MFMA row-in-tile / col-in-tile
    const int g4   = lane >> 4;      // K-group
    const int ro   = g4 << 2;        // C-layout row offset

    const float* Wih  = dir ? b_Wih  : f_Wih;
    const float* Whh  = dir ? b_Whh  : f_Whh;
    const float* bih  = dir ? b_bih  : f_bih;
    const float* bhh  = dir ? b_bhh  : f_bhh;
    const float* Wout = dir ? b_Wout : f_Wout;
    float gam = dir ? b_gamma[0] : f_gamma[0];
    gam = fminf(fmaxf(gam, 1e-4f), 10.0f);
    const float bo = dir ? b_bout[0] : f_bout[0];

    // ---- A-fragments (held for kernel lifetime; MFMA-only operands -> AGPRs)
    // Whh r,z rows 0..127: 8 M-tiles x 2 K-steps, hi & lo copies
    U4 Ahi_rz[8][2], Alo_rz[8][2];
#pragma unroll
    for (int t = 0; t < 8; ++t)
#pragma unroll
        for (int s = 0; s < 2; ++s) {
            const float* wp = Whh + (size_t)(t * 16 + m) * HH + s * 32 + g4 * 8;
            float4 q0 = *(const float4*)wp;
            float4 q1 = *(const float4*)(wp + 4);
            float f[8] = {q0.x, q0.y, q0.z, q0.w, q1.x, q1.y, q1.z, q1.w};
            unsigned hv[4], lv[4];
#pragma unroll
            for (int r2 = 0; r2 < 4; ++r2) {
                unsigned h0, l0, h1, l1;
                split_(f[2 * r2], h0, l0);
                split_(f[2 * r2 + 1], h1, l1);
                hv[r2] = h0 | (h1 << 16);
                lv[r2] = l0 | (l1 << 16);
            }
            Ahi_rz[t][s] = U4{hv[0], hv[1], hv[2], hv[3]};
            Alo_rz[t][s] = U4{lv[0], lv[1], lv[2], lv[3]};
        }
    // Whh n rows 128..191: 4 M-tiles x 2 K-steps
    U4 Ahi_nh[4][2], Alo_nh[4][2];
#pragma unroll
    for (int t = 0; t < 4; ++t)
#pragma unroll
        for (int s = 0; s < 2; ++s) {
            const float* wp = Whh + (size_t)(128 + t * 16 + m) * HH + s * 32 + g4 * 8;
            float4 q0 = *(const float4*)wp;
            float4 q1 = *(const float4*)(wp + 4);
            float f[8] = {q0.x, q0.y, q0.z, q0.w, q1.x, q1.y, q1.z, q1.w};
            unsigned hv[4], lv[4];
#pragma unroll
            for (int r2 = 0; r2 < 4; ++r2) {
                unsigned h0, l0, h1, l1;
                split_(f[2 * r2], h0, l0);
                split_(f[2 * r2 + 1], h1, l1);
                hv[r2] = h0 | (h1 << 16);
                lv[r2] = l0 | (l1 << 16);
            }
            Ahi_nh[t][s] = U4{hv[0], hv[1], hv[2], hv[3]};
            Alo_nh[t][s] = U4{lv[0], lv[1], lv[2], lv[3]};
        }
    // Wih interleaved hi/lo on K (K=32 = 2x16): elem2r=W_hi[d], 2r+1=W_lo[d]
    U4 Agi[12];
#pragma unroll
    for (int t = 0; t < 12; ++t) {
        const float* wp = Wih + (size_t)(t * 16 + m) * DD + g4 * 4;
        float4 q = *(const float4*)wp;
        float f[4] = {q.x, q.y, q.z, q.w};
        unsigned v[4];
#pragma unroll
        for (int r2 = 0; r2 < 4; ++r2) {
            unsigned h0, l0;
            split_(f[r2], h0, l0);
            v[r2] = h0 | (l0 << 16);
        }
        Agi[t] = U4{v[0], v[1], v[2], v[3]};
    }
    // Wout: A row0 = wo_hi (dup in K-pair), row1 = wo_lo; K doubled (hi/lo of h)
    U4 Ay[4];
#pragma unroll
    for (int ks = 0; ks < 4; ++ks) {
        unsigned v[4];
#pragma unroll
        for (int r2 = 0; r2 < 4; ++r2) {
            int d = ks * 16 + g4 * 4 + r2;
            unsigned h0, l0;
            split_(Wout[d], h0, l0);
            unsigned uh = h0 | (h0 << 16);
            unsigned ul = l0 | (l0 << 16);
            v[r2] = (m == 0) ? uh : ((m == 1) ? ul : 0u);
        }
        Ay[ks] = U4{v[0], v[1], v[2], v[3]};
    }

    const float br  = bih[lane]      + bhh[lane];
    const float bz  = bih[64 + lane] + bhh[64 + lane];
    const float bni = bih[128 + lane];
    const float bnh = bhh[128 + lane];

    // per-lane byte-perm selector: col0 lanes take hi16 halves, col1 lo16
    const unsigned sel = (m == 1) ? 0x07060302u : 0x05040100u;
    const int ibase = g4 * 32;   // bpermute byte base

    __shared__ alignas(16) unsigned sh_x[CH * XS];     // packed x chunk
    __shared__ alignas(16) float    sh_gi[CH * GS];    // Wih*x for chunk
    __shared__ alignas(16) float    sh_gh[2 * 192];    // per-step Whh*h_bar (cols hi,lo)
    __shared__ alignas(16) unsigned sh_hb[CH * HS];    // packed h (for y)
    __shared__ float sh_dcy[CH + 1];

    float h_reg = 0.0f;      // lane j holds h[j]
    unsigned hb = 0;         // packed h_bar for the *next* step (decay applied)
    float* yd = out + (size_t)(1 + dir) * (BB * LL);

#pragma unroll 1
    for (int c = 0; c < LL / CH; ++c) {
        // ---- stage x (packed f16 hi/lo) and decay factors
#pragma unroll
        for (int q = 0; q < 2; ++q) {
            int j  = q * 64 + lane;          // 0..127 float4s
            int sl = j >> 2;                 // chunk-local step
            int dg = j & 3;
            int t  = dir ? (LL - 1 - (c * CH + sl)) : (c * CH + sl);
            float4 v = *(const float4*)(x + ((size_t)b * LL + t) * DD + dg * 4);
            U4 p = U4{pack_hl(v.x), pack_hl(v.y), pack_hl(v.z), pack_hl(v.w)};
            *(U4*)&sh_x[sl * XS + dg * 4] = p;
        }
        if (lane <= CH) {
            int g = c * CH + lane;
            int gc = (g > LL - 1) ? (LL - 1) : g;
            int t  = dir ? (LL - 1 - gc) : gc;
            float dv = dt[(size_t)b * LL + t];
            dv = fminf(fmaxf(dv, 0.0f), 1e6f);
            sh_dcy[lane] = __expf(-gam * dv);
        }
        // single wave: program order + compiler lgkmcnt waits; no barrier needed

        // ---- gi = Wih * x for the whole chunk (16 steps per MFMA column set)
#pragma unroll
        for (int nt = 0; nt < 2; ++nt) {
            int scol = nt * 16 + m;          // chunk-local step this col handles
            U4 p = *(const U4*)&sh_x[scol * XS + g4 * 4];
            U4 bhf = U4{__builtin_amdgcn_perm(p.x, p.x, 0x01000100u),
                        __builtin_amdgcn_perm(p.y, p.y, 0x01000100u),
                        __builtin_amdgcn_perm(p.z, p.z, 0x01000100u),
                        __builtin_amdgcn_perm(p.w, p.w, 0x01000100u)};
            U4 blf = U4{__builtin_amdgcn_perm(p.x, p.x, 0x03020302u),
                        __builtin_amdgcn_perm(p.y, p.y, 0x03020302u),
                        __builtin_amdgcn_perm(p.z, p.z, 0x03020302u),
                        __builtin_amdgcn_perm(p.w, p.w, 0x03020302u)};
            half8 Bh = h8(bhf), Bl = h8(blf);
#pragma unroll
            for (int t = 0; t < 12; ++t) {
                floatx4 a = {0.0f, 0.0f, 0.0f, 0.0f};
                a = MFMA(h8(Agi[t]), Bh, a);   // W*x_hi
                a = MFMA(h8(Agi[t]), Bl, a);   // + W*x_lo
                *(floatx4*)&sh_gi[scol * GS + t * 16 + ro] = a;
            }
        }

        // ---- recurrent steps
#pragma unroll 1
        for (int i = 0; i < CH; ++i) {
            // B-fragments for h_bar from register hb via bpermute
            unsigned pa, pb;
            U4 f0, f1;
            pa = (unsigned)__builtin_amdgcn_ds_bpermute(ibase + 0,  (int)hb);
            pb = (unsigned)__builtin_amdgcn_ds_bpermute(ibase + 4,  (int)hb);
            f0.x = __builtin_amdgcn_perm(pb, pa, sel);
            pa = (unsigned)__builtin_amdgcn_ds_bpermute(ibase + 8,  (int)hb);
            pb = (unsigned)__builtin_amdgcn_ds_bpermute(ibase + 12, (int)hb);
            f0.y = __builtin_amdgcn_perm(pb, pa, sel);
            pa = (unsigned)__builtin_amdgcn_ds_bpermute(ibase + 16, (int)hb);
            pb = (unsigned)__builtin_amdgcn_ds_bpermute(ibase + 20, (int)hb);
            f0.z = __builtin_amdgcn_perm(pb, pa, sel);
            pa = (unsigned)__builtin_amdgcn_ds_bpermute(ibase + 24, (int)hb);
            pb = (unsigned)__builtin_amdgcn_ds_bpermute(ibase + 28, (int)hb);
            f0.w = __builtin_amdgcn_perm(pb, pa, sel);
            pa = (unsigned)__builtin_amdgcn_ds_bpermute(ibase + 128, (int)hb);
            pb = (unsigned)__builtin_amdgcn_ds_bpermute(ibase + 132, (int)hb);
            f1.x = __builtin_amdgcn_perm(pb, pa, sel);
            pa = (unsigned)__builtin_amdgcn_ds_bpermute(ibase + 136, (int)hb);
            pb = (unsigned)__builtin_amdgcn_ds_bpermute(ibase + 140, (int)hb);
            f1.y = __builtin_amdgcn_perm(pb, pa, sel);
            pa = (unsigned)__builtin_amdgcn_ds_bpermute(ibase + 144, (int)hb);
            pb = (unsigned)__builtin_amdgcn_ds_bpermute(ibase + 148, (int)hb);
            f1.z = __builtin_amdgcn_perm(pb, pa, sel);
            pa = (unsigned)__builtin_amdgcn_ds_bpermute(ibase + 152, (int)hb);
            pb = (unsigned)__builtin_amdgcn_ds_bpermute(ibase + 156, (int)hb);
            f1.w = __builtin_amdgcn_perm(pb, pa, sel);
            half8 B0 = h8(f0), B1 = h8(f1);

            floatx4 arz[8], anh[4];
#pragma unroll
            for (int t = 0; t < 8; ++t) {
                floatx4 a = {0.0f, 0.0f, 0.0f, 0.0f};
                a = MFMA(h8(Alo_rz[t][0]), B0, a);
                a = MFMA(h8(Ahi_rz[t][0]), B0, a);
                a = MFMA(h8(Alo_rz[t][1]), B1, a);
                a = MFMA(h8(Ahi_rz[t][1]), B1, a);
                arz[t] = a;
            }
#pragma unroll
            for (int t = 0; t < 4; ++t) {
                floatx4 a = {0.0f, 0.0f, 0.0f, 0.0f};
                a = MFMA(h8(Alo_nh[t][0]), B0, a);
                a = MFMA(h8(Ahi_nh[t][0]), B0, a);
                a = MFMA(h8(Alo_nh[t][1]), B1, a);
                a = MFMA(h8(Ahi_nh[t][1]), B1, a);
                anh[t] = a;
            }
            // C-layout -> per-row LDS (cols 0,1 = hi,lo contributions)
            if (m < 2) {
                float* g = &sh_gh[m * 192 + ro];
#pragma unroll
                for (int t = 0; t < 8; ++t) *(floatx4*)(g + t * 16) = arz[t];
#pragma unroll
                for (int t = 0; t < 4; ++t) *(floatx4*)(g + 128 + t * 16) = anh[t];
            }
            // gates (lane j owns h[j])
            float ghr = sh_gh[lane]       + sh_gh[192 + lane];
            float ghz = sh_gh[64 + lane]  + sh_gh[192 + 64 + lane];
            float ghn = sh_gh[128 + lane] + sh_gh[192 + 128 + lane];
            float gir = sh_gi[i * GS + lane];
            float giz = sh_gi[i * GS + 64 + lane];
            float gin = sh_gi[i * GS + 128 + lane];
            float r = sigmoidf_(ghr + gir + br);
            float z = sigmoidf_(ghz + giz + bz);
            float n = tanhf_((gin + bni) + r * (ghn + bnh));
            float hbar = sh_dcy[i] * h_reg;
            h_reg = n + z * (hbar - n);
            hb = pack_hl(sh_dcy[i + 1] * h_reg);   // h_bar for next step
            sh_hb[i * HS + lane] = pack_hl(h_reg); // for y
        }

        // ---- y for this chunk: Wout * H via MFMA (K doubled hi/lo)
#pragma unroll
        for (int nt = 0; nt < 2; ++nt) {
            floatx4 ay = {0.0f, 0.0f, 0.0f, 0.0f};
#pragma unroll
            for (int ks = 0; ks < 4; ++ks) {
                U4 bu = *(const U4*)&sh_hb[(nt * 16 + m) * HS + ks * 16 + g4 * 4];
                ay = MFMA(h8(Ay[ks]), h8(bu), ay);
            }
            if (lane < 16) {
                int s = c * CH + nt * 16 + lane;
                int t = dir ? (LL - 1 - s) : s;
                yd[(size_t)b * LL + t] = ay[0] + ay[1] + bo;
            }
        }
    }
}

__global__ __launch_bounds__(256) void brios_avg(float* __restrict__ out)
{
    int i = blockIdx.x * blockDim.x + threadIdx.x;
    const int n4 = (BB * LL) / 4;
    if (i < n4) {
        const float4* yf = (const float4*)(out + (size_t)BB * LL);
        const float4* yb = (const float4*)(out + (size_t)2 * BB * LL);
        float4 a = yf[i], b2 = yb[i];
        float4 r;
        r.x = 0.5f * (a.x + b2.x);
        r.y = 0.5f * (a.y + b2.y);
        r.z = 0.5f * (a.z + b2.z);
        r.w = 0.5f * (a.w + b2.w);
        ((float4*)out)[i] = r;
    }
}

extern "C" void kernel_launch(void* const* d_in, const int* in_sizes, int n_in,
                              void* d_out, int out_size, void* d_ws, size_t ws_size,
                              hipStream_t stream) {
    const float* x       = (const float*)d_in[0];
    const float* dt      = (const float*)d_in[1];
    const float* f_Wih   = (const float*)d_in[2];
    const float* f_Whh   = (const float*)d_in[3];
    const float* f_bih   = (const float*)d_in[4];
    const float* f_bhh   = (const float*)d_in[5];
    const float* f_gamma = (const float*)d_in[6];
    const float* f_Wout  = (const float*)d_in[7];
    const float* f_bout  = (const float*)d_in[8];
    const float* b_Wih   = (const float*)d_in[9];
    const float* b_Whh   = (const float*)d_in[10];
    const float* b_bih   = (const float*)d_in[11];
    const float* b_bhh   = (const float*)d_in[12];
    const float* b_gamma = (const float*)d_in[13];
    const float* b_Wout  = (const float*)d_in[14];
    const float* b_bout  = (const float*)d_in[15];
    float* out = (float*)d_out;

    brios_main<<<1024, 64, 0, stream>>>(x, dt,
        f_Wih, f_Whh, f_bih, f_bhh, f_gamma, f_Wout, f_bout,
        b_Wih, b_Whh, b_bih, b_bhh, b_gamma, b_Wout, b_bout, out);

    const int n4 = (BB * LL) / 4;
    brios_avg<<<(n4 + 255) / 256, 256, 0, stream>>>(out);
}

// Round 4
// 814.577 us; speedup vs baseline: 1.5051x; 1.5051x over previous
//
#include <hip/hip_runtime.h>

#define BB 512
#define LL 1024
#define DD 16
#define HH 64
#define CH 16    // timesteps per chunk
#define XP 20    // sh_x row stride (u32), padded
#define GP 196   // sh_gi row stride (f32), padded
#define HP 68    // sh_hn row stride (u32), padded

typedef _Float16 half8 __attribute__((ext_vector_type(8)));
typedef float floatx4 __attribute__((ext_vector_type(4)));

struct U4 { unsigned x, y, z, w; };

__device__ __forceinline__ float sigmoidf_(float x) {
    return __builtin_amdgcn_rcpf(1.0f + __expf(-x));
}
__device__ __forceinline__ float tanhf_(float x) {
    x = fminf(fmaxf(x, -15.0f), 15.0f);
    float e = __expf(2.0f * x);
    return (e - 1.0f) * __builtin_amdgcn_rcpf(e + 1.0f);
}
// split v into f16 hi + f16 lo (v ~= hi + lo, rel err ~2^-22)
__device__ __forceinline__ void split_(float v, unsigned& h, unsigned& l) {
    _Float16 hf = (_Float16)v;
    float rr = v - (float)hf;
    _Float16 lf = (_Float16)rr;
    h = (unsigned)__builtin_bit_cast(unsigned short, hf);
    l = (unsigned)__builtin_bit_cast(unsigned short, lf);
}
__device__ __forceinline__ unsigned pack_hl(float v) {
    unsigned h, l; split_(v, h, l);
    return h | (l << 16);
}
__device__ __forceinline__ float unpack_hl(unsigned u) {
    _Float16 a = __builtin_bit_cast(_Float16, (unsigned short)(u & 0xffffu));
    _Float16 b = __builtin_bit_cast(_Float16, (unsigned short)(u >> 16));
    return (float)a + (float)b;
}
__device__ __forceinline__ half8 h8(U4 u) { return __builtin_bit_cast(half8, u); }

#define MFMA(a, b, c) __builtin_amdgcn_mfma_f32_16x16x32_f16((a), (b), (c), 0, 0, 0)

// Block = 4 waves, 2 sequences (same direction). Wave w owns gate-unit group
// w (units 16w..16w+15): r-tile w, z-tile 4+w, n-tile 8+w -> 12 MFMAs/step
// serving both seqs (B cols 0-3 = seq0 hi/lo, seq1 hi/lo). Gates wave-local;
// one barrier per step (double-buffered packed-h). 512 blocks -> 2 blocks/CU,
// 2 waves/SIMD. All weights in arch VGPRs (no AGPR copies).
__global__ __launch_bounds__(256, 2) void brios_main(
    const float* __restrict__ x, const float* __restrict__ dt,
    const float* __restrict__ f_Wih, const float* __restrict__ f_Whh,
    const float* __restrict__ f_bih, const float* __restrict__ f_bhh,
    const float* __restrict__ f_gamma, const float* __restrict__ f_Wout,
    const float* __restrict__ f_bout,
    const float* __restrict__ b_Wih, const float* __restrict__ b_Whh,
    const float* __restrict__ b_bih, const float* __restrict__ b_bhh,
    const float* __restrict__ b_gamma, const float* __restrict__ b_Wout,
    const float* __restrict__ b_bout,
    float* __restrict__ out)
{
    const int tid  = threadIdx.x;
    const int wave = tid >> 6;
    const int lane = tid & 63;
    const int m    = lane & 15;
    const int g4   = lane >> 4;
    const int sq0  = blockIdx.x * 2;      // global seq id of slot 0
    const int dir  = sq0 >> 9;            // both seqs same dir (512 % 2 == 0)
    const int bat0 = sq0 & 511;
    const int bat1 = (sq0 + 1) & 511;

    const float* Wih  = dir ? b_Wih  : f_Wih;
    const float* Whh  = dir ? b_Whh  : f_Whh;
    const float* bih  = dir ? b_bih  : f_bih;
    const float* bhh  = dir ? b_bhh  : f_bhh;
    const float* Wout = dir ? b_Wout : f_Wout;
    float gam = dir ? b_gamma[0] : f_gamma[0];
    gam = fminf(fmaxf(gam, 1e-4f), 10.0f);
    const float bo = dir ? b_bout[0] : f_bout[0];

    // ---- Whh A-fragments for this wave's 3 tiles (r,z,n of unit group `wave`)
    U4 Ah[3][2], Al[3][2];
#pragma unroll
    for (int tt = 0; tt < 3; ++tt) {
        int row = tt * 64 + wave * 16 + m;
#pragma unroll
        for (int ks = 0; ks < 2; ++ks) {
            const float* wp = Whh + (size_t)row * HH + ks * 32 + g4 * 8;
            float4 q0 = *(const float4*)wp;
            float4 q1 = *(const float4*)(wp + 4);
            float f[8] = {q0.x, q0.y, q0.z, q0.w, q1.x, q1.y, q1.z, q1.w};
            unsigned hv[4], lv[4];
#pragma unroll
            for (int r2 = 0; r2 < 4; ++r2) {
                unsigned h0, l0, h1, l1;
                split_(f[2*r2], h0, l0);
                split_(f[2*r2+1], h1, l1);
                hv[r2] = h0 | (h1 << 16);
                lv[r2] = l0 | (l1 << 16);
            }
            Ah[tt][ks] = U4{hv[0], hv[1], hv[2], hv[3]};
            Al[tt][ks] = U4{lv[0], lv[1], lv[2], lv[3]};
        }
    }
    // ---- Wih fragments: K-pairs interleave (w_hi, w_lo); B gets dup'd x
    U4 Agi[3];
#pragma unroll
    for (int tt = 0; tt < 3; ++tt) {
        int row = tt * 64 + wave * 16 + m;
        unsigned v[4];
#pragma unroll
        for (int r2 = 0; r2 < 4; ++r2) {
            unsigned h0, l0;
            split_(Wih[(size_t)row * DD + g4 * 4 + r2], h0, l0);
            v[r2] = h0 | (l0 << 16);
        }
        Agi[tt] = U4{v[0], v[1], v[2], v[3]};
    }
    // ---- Wout fragments (waves 0-1 only): row 0 = interleaved (wo_hi, wo_lo)
    U4 Ay[4];
#pragma unroll
    for (int ks = 0; ks < 4; ++ks) {
        unsigned v[4];
#pragma unroll
        for (int r2 = 0; r2 < 4; ++r2) {
            unsigned h0, l0;
            split_(Wout[ks * 16 + g4 * 4 + r2], h0, l0);
            v[r2] = (m == 0) ? (h0 | (l0 << 16)) : 0u;
        }
        Ay[ks] = U4{v[0], v[1], v[2], v[3]};
    }

    // gate-lane constants (lanes 0..31: seq=lane>>4, unit u = wave*16+(lane&15))
    const int gu = wave * 16 + (lane & 15);
    const float br  = bih[gu]       + bhh[gu];
    const float bz  = bih[64 + gu]  + bhh[64 + gu];
    const float bni = bih[128 + gu];
    const float bnh = bhh[128 + gu];

    const unsigned selB = (m & 1) ? 0x07060302u : 0x05040100u;
    const int bseq = (m >> 1) & 1;       // seq this lane's B-column belongs to

    __shared__ alignas(16) unsigned sh_hb[2][2][64];   // dbl-buf packed h_bar
    __shared__ alignas(16) unsigned sh_x[2 * CH][XP];  // packed x chunk
    __shared__ alignas(16) float    sh_gi[2 * CH][GP]; // Wih*x + (row-major 192)
    __shared__ alignas(16) unsigned sh_hn[2 * CH][HP]; // packed h (for y)
    __shared__ alignas(16) float    sh_gh[4][4][3][16];// [wave][col][tile][unit]
    __shared__ float sh_dcy[2][CH + 2];

    ((unsigned*)sh_hb)[tid] = 0u;        // 2*2*64 = 256 = blockDim

    float* yd = out + (size_t)(1 + dir) * (BB * LL);

#pragma unroll 1
    for (int c = 0; c < LL / CH; ++c) {
        const int sbase = c * CH;
        const int t_low = dir ? (LL - CH - sbase) : sbase;

        // ---- staging: x by waves 2-3 (coalesced float4 + pack), dt by wave 0
        if (tid >= 128) {
            int t2 = tid - 128;
            int sq = t2 >> 6, q = t2 & 63;
            int tq = q >> 2, d4 = q & 3;
            size_t bb = (sq == 0) ? bat0 : bat1;
            float4 v = *(const float4*)(x + ((size_t)bb * LL + t_low + tq) * DD + d4 * 4);
            int sl = dir ? (CH - 1 - tq) : tq;
            U4 p = U4{pack_hl(v.x), pack_hl(v.y), pack_hl(v.z), pack_hl(v.w)};
            *(U4*)&sh_x[sq * CH + sl][d4 * 4] = p;
        } else if (tid < 2 * (CH + 1)) {
            int sq = tid / (CH + 1), k = tid % (CH + 1);
            int g = sbase + k;
            if (g >= LL) {
                sh_dcy[sq][k] = 1.0f;
            } else {
                size_t bb = (sq == 0) ? bat0 : bat1;
                int t = dir ? (LL - 1 - g) : g;
                float dv = dt[(size_t)bb * LL + t];
                dv = fminf(fmaxf(dv, 0.0f), 1e6f);
                sh_dcy[sq][k] = __expf(-gam * dv);
            }
        }
        __syncthreads();

        // ---- gi = Wih*x for the chunk (wave-local produce->consume)
#pragma unroll
        for (int g = 0; g < 2; ++g) {
            U4 p = *(const U4*)&sh_x[g * CH + m][g4 * 4];
            U4 ph = U4{__builtin_amdgcn_perm(p.x, p.x, 0x01000100u),
                       __builtin_amdgcn_perm(p.y, p.y, 0x01000100u),
                       __builtin_amdgcn_perm(p.z, p.z, 0x01000100u),
                       __builtin_amdgcn_perm(p.w, p.w, 0x01000100u)};
            U4 pl = U4{__builtin_amdgcn_perm(p.x, p.x, 0x03020302u),
                       __builtin_amdgcn_perm(p.y, p.y, 0x03020302u),
                       __builtin_amdgcn_perm(p.z, p.z, 0x03020302u),
                       __builtin_amdgcn_perm(p.w, p.w, 0x03020302u)};
            half8 Bh = h8(ph), Bl = h8(pl);
            floatx4 ga[3] = {{0,0,0,0},{0,0,0,0},{0,0,0,0}};
#pragma unroll
            for (int tt = 0; tt < 3; ++tt) ga[tt] = MFMA(h8(Agi[tt]), Bh, ga[tt]);
#pragma unroll
            for (int tt = 0; tt < 3; ++tt) ga[tt] = MFMA(h8(Agi[tt]), Bl, ga[tt]);
#pragma unroll
            for (int tt = 0; tt < 3; ++tt)
                *(floatx4*)&sh_gi[g * CH + m][tt * 64 + wave * 16 + g4 * 4] = ga[tt];
        }

        // ---- recurrent steps: ONE barrier per step
#pragma unroll 1
        for (int i = 0; i < CH; ++i) {
            // B fragments from packed h_bar (buffer i&1)
            const unsigned* hbuf = &sh_hb[i & 1][bseq][0];
            U4 d0 = *(const U4*)&hbuf[g4 * 8];
            U4 d1 = *(const U4*)&hbuf[g4 * 8 + 4];
            U4 e0 = *(const U4*)&hbuf[32 + g4 * 8];
            U4 e1 = *(const U4*)&hbuf[32 + g4 * 8 + 4];
            U4 f0 = U4{__builtin_amdgcn_perm(d0.y, d0.x, selB),
                       __builtin_amdgcn_perm(d0.w, d0.z, selB),
                       __builtin_amdgcn_perm(d1.y, d1.x, selB),
                       __builtin_amdgcn_perm(d1.w, d1.z, selB)};
            U4 f1 = U4{__builtin_amdgcn_perm(e0.y, e0.x, selB),
                       __builtin_amdgcn_perm(e0.w, e0.z, selB),
                       __builtin_amdgcn_perm(e1.y, e1.x, selB),
                       __builtin_amdgcn_perm(e1.w, e1.z, selB)};
            half8 B0 = h8(f0), B1 = h8(f1);

            floatx4 a0 = {0,0,0,0}, a1 = {0,0,0,0}, a2 = {0,0,0,0};
            a0 = MFMA(h8(Al[0][0]), B0, a0);
            a1 = MFMA(h8(Al[1][0]), B0, a1);
            a2 = MFMA(h8(Al[2][0]), B0, a2);
            a0 = MFMA(h8(Ah[0][0]), B0, a0);
            a1 = MFMA(h8(Ah[1][0]), B0, a1);
            a2 = MFMA(h8(Ah[2][0]), B0, a2);
            a0 = MFMA(h8(Al[0][1]), B1, a0);
            a1 = MFMA(h8(Al[1][1]), B1, a1);
            a2 = MFMA(h8(Al[2][1]), B1, a2);
            a0 = MFMA(h8(Ah[0][1]), B1, a0);
            a1 = MFMA(h8(Ah[1][1]), B1, a1);
            a2 = MFMA(h8(Ah[2][1]), B1, a2);

            // C cols 0-3 -> wave-private LDS
            if (m < 4) {
                *(floatx4*)&sh_gh[wave][m][0][g4 * 4] = a0;
                *(floatx4*)&sh_gh[wave][m][1][g4 * 4] = a1;
                *(floatx4*)&sh_gh[wave][m][2][g4 * 4] = a2;
            }
            // gates (wave-local): lane<32: seq=lane>>4, unit gu
            if (lane < 32) {
                int sq = lane >> 4, ul = lane & 15;
                float ghr = sh_gh[wave][sq*2][0][ul] + sh_gh[wave][sq*2+1][0][ul];
                float ghz = sh_gh[wave][sq*2][1][ul] + sh_gh[wave][sq*2+1][1][ul];
                float ghn = sh_gh[wave][sq*2][2][ul] + sh_gh[wave][sq*2+1][2][ul];
                const float* gip = sh_gi[sq * CH + i];
                float gir = gip[gu], giz = gip[64 + gu], gin = gip[128 + gu];
                float hbv = unpack_hl(sh_hb[i & 1][sq][gu]);
                float r = sigmoidf_(ghr + gir + br);
                float z = sigmoidf_(ghz + giz + bz);
                float n = tanhf_((gin + bni) + r * (ghn + bnh));
                float hn_ = n + z * (hbv - n);
                sh_hn[sq * CH + i][gu] = pack_hl(hn_);
                sh_hb[(i + 1) & 1][sq][gu] = pack_hl(sh_dcy[sq][i + 1] * hn_);
            }
            __syncthreads();
        }

        // ---- y for the chunk: waves 0-1, seq = wave, cols = steps
        if (wave < 2) {
            floatx4 ay = {0,0,0,0};
#pragma unroll
            for (int ks = 0; ks < 4; ++ks) {
                U4 p = *(const U4*)&sh_hn[wave * CH + m][ks * 16 + g4 * 4];
                U4 ph = U4{__builtin_amdgcn_perm(p.x, p.x, 0x01000100u),
                           __builtin_amdgcn_perm(p.y, p.y, 0x01000100u),
                           __builtin_amdgcn_perm(p.z, p.z, 0x01000100u),
                           __builtin_amdgcn_perm(p.w, p.w, 0x01000100u)};
                U4 pl = U4{__builtin_amdgcn_perm(p.x, p.x, 0x03020302u),
                           __builtin_amdgcn_perm(p.y, p.y, 0x03020302u),
                           __builtin_amdgcn_perm(p.z, p.z, 0x03020302u),
                           __builtin_amdgcn_perm(p.w, p.w, 0x03020302u)};
                ay = MFMA(h8(Ay[ks]), h8(ph), ay);
                ay = MFMA(h8(Ay[ks]), h8(pl), ay);
            }
            if (lane < 16) {
                int s = sbase + lane;
                int t = dir ? (LL - 1 - s) : s;
                size_t bb = (wave == 0) ? bat0 : bat1;
                yd[bb * LL + t] = ay[0] + bo;
            }
        }
        __syncthreads();   // protect sh_hn/sh_x/sh_gi before next staging
    }
}

__global__ __launch_bounds__(256) void brios_avg(float* __restrict__ out)
{
    int i = blockIdx.x * blockDim.x + threadIdx.x;
    const int n4 = (BB * LL) / 4;
    if (i < n4) {
        const float4* yf = (const float4*)(out + (size_t)BB * LL);
        const float4* yb = (const float4*)(out + (size_t)2 * BB * LL);
        float4 a = yf[i], b2 = yb[i];
        float4 r;
        r.x = 0.5f * (a.x + b2.x);
        r.y = 0.5f * (a.y + b2.y);
        r.z = 0.5f * (a.z + b2.z);
        r.w = 0.5f * (a.w + b2.w);
        ((float4*)out)[i] = r;
    }
}

extern "C" void kernel_launch(void* const* d_in, const int* in_sizes, int n_in,
                              void* d_out, int out_size, void* d_ws, size_t ws_size,
                              hipStream_t stream) {
    const float* x       = (const float*)d_in[0];
    const float* dt      = (const float*)d_in[1];
    const float* f_Wih   = (const float*)d_in[2];
    const float* f_Whh   = (const float*)d_in[3];
    const float* f_bih   = (const float*)d_in[4];
    const float* f_bhh   = (const float*)d_in[5];
    const float* f_gamma = (const float*)d_in[6];
    const float* f_Wout  = (const float*)d_in[7];
    const float* f_bout  = (const float*)d_in[8];
    const float* b_Wih   = (const float*)d_in[9];
    const float* b_Whh   = (const float*)d_in[10];
    const float* b_bih   = (const float*)d_in[11];
    const float* b_bhh   = (const float*)d_in[12];
    const float* b_gamma = (const float*)d_in[13];
    const float* b_Wout  = (const float*)d_in[14];
    const float* b_bout  = (const float*)d_in[15];
    float* out = (float*)d_out;

    brios_main<<<512, 256, 0, stream>>>(x, dt,
        f_Wih, f_Whh, f_bih, f_bhh, f_gamma, f_Wout, f_bout,
        b_Wih, b_Whh, b_bih, b_bhh, b_gamma, b_Wout, b_bout, out);

    const int n4 = (BB * LL) / 4;
    brios_avg<<<(n4 + 255) / 256, 256, 0, stream>>>(out);
}